// Round 4
// baseline (431.217 us; speedup 1.0000x reference)
//
#include <hip/hip_runtime.h>

// Problem constants (fixed by setup_inputs): B=8, C=19, H=512, W=1024
#define NCLASS 19
#define NCNT   (3 * NCLASS)      // 57 counters: pred[19] | true[19] | inter[19]
#define HW (512 * 1024)          // 2^19 pixels per (b, c) plane
#define NB 8
#define NPIX (NB * HW)           // 4,194,304 pixels
#define NGROUP (NPIX / 4)        // 1,048,576 float4 groups
#define GPB 256                  // float4 groups per block -> 1024 px/block
#define GRID (NGROUP / GPB)      // 4096 blocks

typedef float v4f __attribute__((ext_vector_type(4)));
typedef int   v4i __attribute__((ext_vector_type(4)));
typedef unsigned int v4u __attribute__((ext_vector_type(4)));

// ws layout: partials[NCNT][GRID] u32 = 934 KB, counter-major. Every slot is
// written unconditionally by its block -> NO zero-init pass, 2 launches total.

// R2 lesson (VGPR=36, 202 GB/s): plain loads get sunk 1-deep by the compiler.
// R3 lesson: sched_barrier(0) un-sinks them (<190us) but blocks compare/load
// overlap and cost a 3rd launch -> 424 total vs 403.
// This round: sched_barrier(0x7) = ALU|VALU|SALU may cross, VMEM may NOT.
// The 19 dwordx4 loads stay clustered (full MLP) while the argmax chain can
// be hoisted into the load-return tail by the scheduler.
// Plain (not nontemporal) loads keep L3 retention: R2 measured FETCH=164MB
// of 320MB -> ~156MB served by Infinity Cache across iterations.
__global__ __launch_bounds__(256, 4) void iou_count_kernel(
    const float* __restrict__ preds,
    const int* __restrict__ targets,
    unsigned int* __restrict__ partials)
{
    __shared__ unsigned int s_cnt[NCNT];   // pred | true | inter

    const int t = threadIdx.x;
    if (t < NCNT) s_cnt[t] = 0u;
    __syncthreads();

    // Block spans 256 consecutive float4 groups = 1024 px; 512 blocks per
    // batch plane, so every block sits inside one plane and every wave load
    // is a contiguous 1 KB dwordx4 access.
    const int g  = blockIdx.x * GPB + t;     // global float4-group id
    const int p0 = g << 2;                   // first pixel of this thread
    const int b  = p0 >> 19;                 // HW == 2^19
    const int hw = p0 & (HW - 1);
    const size_t plane4 = HW / 4;            // plane stride in float4 units

    const v4f* __restrict__ base =
        (const v4f*)(preds + (size_t)b * NCLASS * HW) + (hw >> 2);
    const v4i* __restrict__ tgt4 = (const v4i*)targets + g;

    // Phase 1: issue ALL 20 loads (19 class vectors + targets).
    v4f v[NCLASS];
    #pragma unroll
    for (int c = 0; c < NCLASS; ++c)
        v[c] = base[(size_t)c * plane4];
    const v4i ta = *tgt4;
    // VMEM pinned above this point; ALU free to cross (overlap with returns).
    __builtin_amdgcn_sched_barrier(0x7);

    // Phase 2: argmax over classes (strict > keeps first max, matching
    // jnp.argmax; softmax is monotonic so argmax(logits) == argmax(probs)).
    v4f m = v[0];
    int ix = 0, iy = 0, iz = 0, iw = 0;
    #pragma unroll
    for (int c = 1; c < NCLASS; ++c) {
        if (v[c].x > m.x) { m.x = v[c].x; ix = c; }
        if (v[c].y > m.y) { m.y = v[c].y; iy = c; }
        if (v[c].z > m.z) { m.z = v[c].z; iz = c; }
        if (v[c].w > m.w) { m.w = v[c].w; iw = c; }
    }

    atomicAdd(&s_cnt[ix], 1u);
    atomicAdd(&s_cnt[iy], 1u);
    atomicAdd(&s_cnt[iz], 1u);
    atomicAdd(&s_cnt[iw], 1u);

    atomicAdd(&s_cnt[NCLASS + ta.x], 1u);
    atomicAdd(&s_cnt[NCLASS + ta.y], 1u);
    atomicAdd(&s_cnt[NCLASS + ta.z], 1u);
    atomicAdd(&s_cnt[NCLASS + ta.w], 1u);

    if (ix == ta.x) atomicAdd(&s_cnt[2 * NCLASS + ix], 1u);
    if (iy == ta.y) atomicAdd(&s_cnt[2 * NCLASS + iy], 1u);
    if (iz == ta.z) atomicAdd(&s_cnt[2 * NCLASS + iz], 1u);
    if (iw == ta.w) atomicAdd(&s_cnt[2 * NCLASS + iw], 1u);

    __syncthreads();
    // Counter-major: partials[j*GRID + bid]. Consecutive blocks write
    // consecutive dwords for fixed j -> L2 write-combines. No atomics, no
    // init dependency.
    if (t < NCNT) partials[t * GRID + blockIdx.x] = s_cnt[t];
}

__global__ __launch_bounds__(1024) void iou_finalize_kernel(
    const unsigned int* __restrict__ partials,
    float* __restrict__ out)
{
    // 16 threads per counter, each reads v4u -> 64 entries per iter,
    // 64 iters cover GRID=4096 entries. Coalesced 256 B per 16-lane group.
    __shared__ unsigned int s_red[NCNT][16];
    __shared__ unsigned int s_tot[NCNT];
    __shared__ float s_iou[NCLASS];

    const int t = threadIdx.x;
    const int j = t >> 4;          // counter index, valid for j < 57
    const int k = t & 15;

    if (j < NCNT) {
        const v4u* __restrict__ p4 = (const v4u*)(partials + j * GRID);
        unsigned int s = 0;
        #pragma unroll
        for (int i = 0; i < 64; ++i) {
            const v4u v = p4[i * 16 + k];
            s += v.x + v.y + v.z + v.w;
        }
        s_red[j][k] = s;
    }
    __syncthreads();
    if (j < NCNT && k == 0) {
        unsigned int s = 0;
        #pragma unroll
        for (int i = 0; i < 16; ++i) s += s_red[j][i];
        s_tot[j] = s;
    }
    __syncthreads();

    if (t < NCLASS) {
        const unsigned int pc = s_tot[t];
        const unsigned int tc = s_tot[NCLASS + t];
        const unsigned int ic = s_tot[2 * NCLASS + t];
        unsigned int un = pc + tc - ic;
        un = un > 1u ? un : 1u;                    // max(union, 1)
        const float iou = (tc > 0u) ? ((float)ic / (float)un) : 0.0f;
        s_iou[t] = iou;
        if (t >= 1) out[t - 1] = iou;              // iou = iou_all[1:]
    }
    __syncthreads();
    if (t == 0) {
        float s = 0.0f;
        for (int c = 1; c < NCLASS; ++c) s += s_iou[c];
        out[NCLASS - 1] = s / (float)(NCLASS - 1); // mean_iou at out[18]
    }
}

extern "C" void kernel_launch(void* const* d_in, const int* in_sizes, int n_in,
                              void* d_out, int out_size, void* d_ws, size_t ws_size,
                              hipStream_t stream) {
    const float* preds  = (const float*)d_in[0];
    const int* targets  = (const int*)d_in[1];
    float* out          = (float*)d_out;
    unsigned int* partials = (unsigned int*)d_ws;   // NCNT*GRID*4 = 934 KB

    iou_count_kernel<<<GRID, 256, 0, stream>>>(preds, targets, partials);
    iou_finalize_kernel<<<1, 1024, 0, stream>>>(partials, out);
}